// Round 7
// baseline (189.439 us; speedup 1.0000x reference)
//
#include <hip/hip_runtime.h>
#include <hip/hip_bf16.h>

#define B 8
#define T 1024
#define E 128
#define H 8
#define DH 16
#define E3 384

typedef __attribute__((ext_vector_type(8))) short short8;
typedef __attribute__((ext_vector_type(4))) short short4s;
typedef __attribute__((ext_vector_type(4))) float f32x4;

// fp32 -> bf16 (round-to-nearest-even), bit pattern in a short
static __device__ inline short bf16s(float x) {
    union { float f; unsigned u; } v; v.f = x;
    unsigned r = v.u + 0x7fffu + ((v.u >> 16) & 1u);
    return (short)(r >> 16);
}

// ---------------------------------------------------------------------------
// Kernel 0: pack win into bf16 K=256 complex-packed layout.
// ---------------------------------------------------------------------------
__global__ void pack_win_kernel(
    const float* __restrict__ win_re, const float* __restrict__ win_im,
    short* __restrict__ Wp_re, short* __restrict__ Wp_im)
{
    int idx = blockIdx.x * 256 + threadIdx.x;   // [0, 384*128)
    int j = idx >> 7, e = idx & 127;
    float wr = win_re[idx], wi = win_im[idx];
    Wp_re[j*256 + e]       = bf16s(wr);
    Wp_re[j*256 + 128 + e] = bf16s(-wi);
    Wp_im[j*256 + e]       = bf16s(wi);
    Wp_im[j*256 + 128 + e] = bf16s(wr);
}

// ---------------------------------------------------------------------------
// Kernel 1: fuse output linears: wf = wt @ wout, bf = wt @ bout + bt (complex)
// Emits wf directly in packed bf16 layout, bias in fp32.
// ---------------------------------------------------------------------------
__global__ void fuse_weights_kernel(
    const float* __restrict__ wout_re, const float* __restrict__ wout_im,
    const float* __restrict__ bout_re, const float* __restrict__ bout_im,
    const float* __restrict__ wt_re,   const float* __restrict__ wt_im,
    const float* __restrict__ bt_re,   const float* __restrict__ bt_im,
    short* __restrict__ Wfp_re, short* __restrict__ Wfp_im,
    float* __restrict__ bf_re, float* __restrict__ bf_im)
{
    int idx = blockIdx.x * blockDim.x + threadIdx.x;   // [0, E*E)
    int j = idx >> 7, e = idx & 127;
    float ar = 0.f, ai = 0.f;
    for (int m = 0; m < E; ++m) {
        float tr = wt_re[j*E+m], ti = wt_im[j*E+m];
        float pr = wout_re[m*E+e], pi = wout_im[m*E+e];
        ar += tr*pr - ti*pi;
        ai += tr*pi + ti*pr;
    }
    Wfp_re[j*256 + e]       = bf16s(ar);
    Wfp_re[j*256 + 128 + e] = bf16s(-ai);
    Wfp_im[j*256 + e]       = bf16s(ai);
    Wfp_im[j*256 + 128 + e] = bf16s(ar);
    if (idx < E) {
        float br = bt_re[idx], bi = bt_im[idx];
        for (int m = 0; m < E; ++m) {
            float tr = wt_re[idx*E+m], ti = wt_im[idx*E+m];
            br += tr*bout_re[m] - ti*bout_im[m];
            bi += tr*bout_im[m] + ti*bout_re[m];
        }
        bf_re[idx] = br; bf_im[idx] = bi;
    }
}

// ---------------------------------------------------------------------------
// Kernel 2: MFMA QKV projection, fragment-ready packed outputs.
// Grid 1024: id = ttile*2 + half; half=0 computes all re outputs, half=1 im.
//   Qpk/Kpk : bf16 [bh][t][32]; q scaled 0.25
//   Vtre/Vtim: bf16 [bh][dh][T] transposed + pi-interleaved per 32-t block:
//     key tloc stored at pos = (tloc>>2)*8 + (tloc&3)            (tloc<16)
//                        pos = ((tloc-16)>>2)*8 + 4 + ((tloc-16)&3) (else)
//     matching attention's in-register S^T->B-fragment key order.
// ---------------------------------------------------------------------------
__global__ __launch_bounds__(256) void qkv_mfma_kernel(
    const float* __restrict__ x_re, const float* __restrict__ x_im,
    const short* __restrict__ Wp_re, const short* __restrict__ Wp_im,
    const float* __restrict__ bin_re, const float* __restrict__ bin_im,
    short* __restrict__ Qpk, short* __restrict__ Kpk,
    short* __restrict__ Vtre, short* __restrict__ Vtim)
{
    int tid  = threadIdx.x;
    int wave = tid >> 6, lane = tid & 63;
    int col  = lane & 15, quad = lane >> 4;
    int id = blockIdx.x;               // [0, 1024)
    int ttile = id >> 1;
    int is_im = id & 1;
    int b  = ttile >> 6;
    int tb = (ttile & 63) * 16 + col;  // t within batch (this lane's n index)

    // X fragments for all 8 k-tiles: B[n=col][k=quad*8+jj]
    short8 xf[8];
    #pragma unroll
    for (int kt = 0; kt < 8; ++kt) {
        const float* xs = (kt < 4) ? x_re : x_im;
        int e0 = (kt & 3) * 32 + quad * 8;
        #pragma unroll
        for (int jj = 0; jj < 8; ++jj) {
            float xv = xs[((long)(b*E + e0 + jj))*T + tb];
            xf[kt][jj] = bf16s(xv);
        }
    }

    const short* Wsel = is_im ? Wp_im : Wp_re;
    const float* bias = is_im ? bin_im : bin_re;
    const f32x4 zero = {0.f,0.f,0.f,0.f};

    for (int ni = 0; ni < 6; ++ni) {
        int jt = wave * 6 + ni;            // [0,24): which*8 + h
        const short* wrow = &Wsel[(jt*16 + col)*256 + quad*8];
        f32x4 acc = zero;
        #pragma unroll
        for (int kt = 0; kt < 8; ++kt) {
            short8 af = *(const short8*)(wrow + kt*32);
            acc = __builtin_amdgcn_mfma_f32_16x16x32_bf16(af, xf[kt], acc, 0, 0, 0);
        }
        int which = jt >> 3;               // 0 q, 1 k, 2 v
        int h = jt & 7;
        float scale = (which == 0) ? 0.25f : 1.0f;
        f32x4 res;
        #pragma unroll
        for (int r = 0; r < 4; ++r) {
            int jg = which*128 + h*16 + quad*4 + r;
            res[r] = (acc[r] + bias[jg]) * scale;
        }
        long bh = b*H + h;
        if (which == 2) {
            // V transposed + pi-interleaved: Vt[bh][dh][blk*32 + pos]
            short* vt = is_im ? Vtim : Vtre;
            int tloc = tb & 31, tblk = tb & ~31;
            int u  = tloc & 15;
            int kk = (u >> 2)*8 + (u & 3) + ((tloc >= 16) ? 4 : 0);
            #pragma unroll
            for (int r = 0; r < 4; ++r)
                vt[(bh*DH + quad*4 + r)*T + tblk + kk] = bf16s(res[r]);
        } else {
            short* qk = (which == 0) ? Qpk : Kpk;
            short4s pk;
            #pragma unroll
            for (int r = 0; r < 4; ++r) pk[r] = bf16s(res[r]);
            *(short4s*)&qk[(bh*T + tb)*32 + is_im*16 + quad*4] = pk;
        }
    }
}

// ---------------------------------------------------------------------------
// Kernel 3: MFMA flash attention -- NO LDS, fully in-register P.
// S^T tiles: sT = mfma(kfrag, qfrag) -> lane(col,quad) reg r holds
// S[key=quad*4+r][q=col]. exp() in place; the 8 values (2 tiles) ARE a
// B-operand fragment P[q=col][kpos=quad*8+j] under key-permutation pi
// (V stored pi-interleaved by qkv). PV: oacc = mfma(vtfrag, pfrag, oacc)
// -> O^T (lane q=col, d=quad*4+r). Rowsum via ones-MFMA.
// Grid 1D: id = qt*64 + bh (XCD pinning).
// ---------------------------------------------------------------------------
__global__ __launch_bounds__(256) void attn_mfma_kernel(
    const short* __restrict__ Qpk, const short* __restrict__ Kpk,
    const short* __restrict__ Vtre, const short* __restrict__ Vtim,
    short* __restrict__ Opk)
{
    int id   = blockIdx.x;
    int bh   = id & 63;
    int q0   = (id >> 6) * 64;
    int tid  = threadIdx.x;
    int wave = tid >> 6;
    int lane = tid & 63;
    int col  = lane & 15;
    int quad = lane >> 4;

    long kq_base = (long)bh * T * 32;
    long vt_base = (long)bh * DH * T + (long)col * T;

    short8 qfrag = *(const short8*)&Qpk[kq_base + (long)(q0 + wave*16 + col)*32 + quad*8];

    const short* Kb = &Kpk[kq_base];
    const short* Vr = &Vtre[vt_base];
    const short* Vi = &Vtim[vt_base];

    short8 ones;
    #pragma unroll
    for (int i = 0; i < 8; ++i) ones[i] = (short)0x3F80;   // bf16 1.0

    f32x4 oaccr = {0.f,0.f,0.f,0.f};
    f32x4 oacci = {0.f,0.f,0.f,0.f};
    f32x4 lacc  = {0.f,0.f,0.f,0.f};
    const f32x4 zero = {0.f,0.f,0.f,0.f};

    // prologue: tile 0 fragments
    short8 kf0 = *(const short8*)&Kb[(long)(col)*32 + quad*8];
    short8 kf1 = *(const short8*)&Kb[(long)(16 + col)*32 + quad*8];
    short8 vr  = *(const short8*)&Vr[quad*8];
    short8 vi  = *(const short8*)&Vi[quad*8];

    #pragma unroll 2
    for (int i = 0; i < 32; ++i) {
        // prefetch tile i+1 (OOB at i=31 lands in adjacent ws arrays -- unused)
        int k1 = (i + 1) * 32;
        short8 kf0n = *(const short8*)&Kb[(long)(k1 + col)*32 + quad*8];
        short8 kf1n = *(const short8*)&Kb[(long)(k1 + 16 + col)*32 + quad*8];
        short8 vrn  = *(const short8*)&Vr[k1 + quad*8];
        short8 vin  = *(const short8*)&Vi[k1 + quad*8];

        // transposed scores: lane reg r = S[key=quad*4+r(+16)][q=col]
        f32x4 s0 = __builtin_amdgcn_mfma_f32_16x16x32_bf16(kf0, qfrag, zero, 0, 0, 0);
        f32x4 s1 = __builtin_amdgcn_mfma_f32_16x16x32_bf16(kf1, qfrag, zero, 0, 0, 0);

        // exp -> in-register B-fragment P[q=col][kpos=quad*8+j] (pi order)
        short8 pf;
        #pragma unroll
        for (int r = 0; r < 4; ++r) {
            pf[r]     = bf16s(__expf(s0[r]));
            pf[4 + r] = bf16s(__expf(s1[r]));
        }

        oaccr = __builtin_amdgcn_mfma_f32_16x16x32_bf16(vr, pf, oaccr, 0, 0, 0);
        oacci = __builtin_amdgcn_mfma_f32_16x16x32_bf16(vi, pf, oacci, 0, 0, 0);
        lacc  = __builtin_amdgcn_mfma_f32_16x16x32_bf16(ones, pf, lacc, 0, 0, 0);

        kf0 = kf0n; kf1 = kf1n; vr = vrn; vi = vin;
    }

    // lacc rows identical (ones-A): lacc[r] = rowsum for q=col
    float inv = 1.0f / lacc[0];
    int b = bh >> 3, h = bh & 7;
    int q = q0 + wave*16 + col;
    long orow = ((long)(b*T + q))*256 + h*16 + quad*4;
    short4s pr, pi_;
    #pragma unroll
    for (int r = 0; r < 4; ++r) {
        pr[r]  = bf16s(oaccr[r] * inv);     // d = quad*4 + r
        pi_[r] = bf16s(oacci[r] * inv);
    }
    *(short4s*)&Opk[orow]       = pr;
    *(short4s*)&Opk[orow + 128] = pi_;
}

// ---------------------------------------------------------------------------
// Kernel 4: MFMA output projection, conversion-free B-operand from Opk.
// D[j][t] = sum_k Wf[j][k]*O[t][k], K=256. Scatter-store to out [2,B,E,T].
// ---------------------------------------------------------------------------
__global__ __launch_bounds__(256) void outproj_mfma_kernel(
    const short* __restrict__ Opk,
    const short* __restrict__ Wfp_re, const short* __restrict__ Wfp_im,
    const float* __restrict__ bf_re, const float* __restrict__ bf_im,
    float* __restrict__ out)
{
    int tid  = threadIdx.x;
    int wave = tid >> 6, lane = tid & 63;
    int col  = lane & 15, quad = lane >> 4;
    int ttile = blockIdx.x;            // [0,512)
    int b  = ttile >> 6;
    int tb = (ttile & 63) * 16 + col;
    long trow = (long)b*T + tb;

    short8 xf[8];
    #pragma unroll
    for (int kt = 0; kt < 8; ++kt)
        xf[kt] = *(const short8*)&Opk[trow*256 + kt*32 + quad*8];

    const f32x4 zero = {0.f,0.f,0.f,0.f};
    #pragma unroll
    for (int ni = 0; ni < 4; ++ni) {
        int nt = wave * 4 + ni;            // [0,16)
        int is_im = nt >= 8;
        int jt = is_im ? nt - 8 : nt;      // [0,8)
        const short* Wsel = is_im ? Wfp_im : Wfp_re;
        const short* wrow = &Wsel[(jt*16 + col)*256 + quad*8];
        f32x4 acc = zero;
        #pragma unroll
        for (int kt = 0; kt < 8; ++kt) {
            short8 af = *(const short8*)(wrow + kt*32);
            acc = __builtin_amdgcn_mfma_f32_16x16x32_bf16(af, xf[kt], acc, 0, 0, 0);
        }
        const float* bias = is_im ? bf_im : bf_re;
        long part = is_im ? (long)B*E*T : 0;
        #pragma unroll
        for (int r = 0; r < 4; ++r) {
            int j = jt*16 + quad*4 + r;
            out[part + ((long)(b*E + j))*T + tb] = acc[r] + bias[j];
        }
    }
}

// ---------------------------------------------------------------------------
extern "C" void kernel_launch(void* const* d_in, const int* in_sizes, int n_in,
                              void* d_out, int out_size, void* d_ws, size_t ws_size,
                              hipStream_t stream)
{
    const float* x_re    = (const float*)d_in[0];
    const float* x_im    = (const float*)d_in[1];
    const float* win_re  = (const float*)d_in[2];
    const float* win_im  = (const float*)d_in[3];
    const float* bin_re  = (const float*)d_in[4];
    const float* bin_im  = (const float*)d_in[5];
    const float* wout_re = (const float*)d_in[6];
    const float* wout_im = (const float*)d_in[7];
    const float* bout_re = (const float*)d_in[8];
    const float* bout_im = (const float*)d_in[9];
    const float* wt_re   = (const float*)d_in[10];
    const float* wt_im   = (const float*)d_in[11];
    const float* bt_re   = (const float*)d_in[12];
    const float* bt_im   = (const float*)d_in[13];
    float* out = (float*)d_out;

    // workspace layout (shorts/floats)
    short* Qpk  = (short*)d_ws;                       // 64*1024*32 = 2M shorts
    short* Kpk  = Qpk + (long)B*H*T*32;
    short* Vtre = Kpk + (long)B*H*T*32;               // 64*16*1024 = 1M shorts
    short* Vtim = Vtre + (long)B*H*DH*T;
    short* Opk  = Vtim + (long)B*H*DH*T;              // 8*1024*256 = 2M shorts
    short* Wp_re  = Opk + (long)B*T*256;
    short* Wp_im  = Wp_re + E3*256;
    short* Wfp_re = Wp_im + E3*256;
    short* Wfp_im = Wfp_re + E*256;
    float* bf_re  = (float*)(Wfp_im + E*256);
    float* bf_im  = bf_re + E;

    pack_win_kernel<<<dim3(E3*E/256), dim3(256), 0, stream>>>(
        win_re, win_im, Wp_re, Wp_im);

    fuse_weights_kernel<<<dim3(E*E/256), dim3(256), 0, stream>>>(
        wout_re, wout_im, bout_re, bout_im, wt_re, wt_im, bt_re, bt_im,
        Wfp_re, Wfp_im, bf_re, bf_im);

    qkv_mfma_kernel<<<dim3(T*B/16*2), dim3(256), 0, stream>>>(
        x_re, x_im, Wp_re, Wp_im, bin_re, bin_im,
        Qpk, Kpk, Vtre, Vtim);

    attn_mfma_kernel<<<dim3((T/64) * B*H), dim3(256), 0, stream>>>(
        Qpk, Kpk, Vtre, Vtim, Opk);

    outproj_mfma_kernel<<<dim3(T*B/16), dim3(256), 0, stream>>>(
        Opk, Wfp_re, Wfp_im, bf_re, bf_im, out);
}

// Round 8
// 167.606 us; speedup vs baseline: 1.1303x; 1.1303x over previous
//
#include <hip/hip_runtime.h>
#include <hip/hip_bf16.h>

#define B 8
#define T 1024
#define E 128
#define H 8
#define DH 16
#define E3 384

typedef __attribute__((ext_vector_type(8))) short short8;
typedef __attribute__((ext_vector_type(4))) short short4s;
typedef __attribute__((ext_vector_type(4))) float f32x4;

// fp32 -> bf16 (round-to-nearest-even), bit pattern in a short
static __device__ inline short bf16s(float x) {
    union { float f; unsigned u; } v; v.f = x;
    unsigned r = v.u + 0x7fffu + ((v.u >> 16) & 1u);
    return (short)(r >> 16);
}

// exp2 via the HW transcendental (1 inst)
#if __has_builtin(__builtin_amdgcn_exp2f)
static __device__ inline float fexp2(float x) { return __builtin_amdgcn_exp2f(x); }
#else
static __device__ inline float fexp2(float x) { return __builtin_exp2f(x); }
#endif

// pack two fp32 into bf16x2 via v_cvt_pk_bf16_f32
static __device__ inline __hip_bfloat162 pk2(float a, float b) {
    float2 t; t.x = a; t.y = b;
    return __float22bfloat162_rn(t);
}

#define QSCALE 0.36067376022224085f   /* 0.25 * log2(e) */

// ---------------------------------------------------------------------------
// Kernel 0: pack win into bf16 K=256 complex-packed layout.
// ---------------------------------------------------------------------------
__global__ void pack_win_kernel(
    const float* __restrict__ win_re, const float* __restrict__ win_im,
    short* __restrict__ Wp_re, short* __restrict__ Wp_im)
{
    int idx = blockIdx.x * 256 + threadIdx.x;   // [0, 384*128)
    int j = idx >> 7, e = idx & 127;
    float wr = win_re[idx], wi = win_im[idx];
    Wp_re[j*256 + e]       = bf16s(wr);
    Wp_re[j*256 + 128 + e] = bf16s(-wi);
    Wp_im[j*256 + e]       = bf16s(wi);
    Wp_im[j*256 + 128 + e] = bf16s(wr);
}

// ---------------------------------------------------------------------------
// Kernel 1: fuse output linears: wf = wt @ wout, bf = wt @ bout + bt (complex)
// ---------------------------------------------------------------------------
__global__ void fuse_weights_kernel(
    const float* __restrict__ wout_re, const float* __restrict__ wout_im,
    const float* __restrict__ bout_re, const float* __restrict__ bout_im,
    const float* __restrict__ wt_re,   const float* __restrict__ wt_im,
    const float* __restrict__ bt_re,   const float* __restrict__ bt_im,
    short* __restrict__ Wfp_re, short* __restrict__ Wfp_im,
    float* __restrict__ bf_re, float* __restrict__ bf_im)
{
    int idx = blockIdx.x * blockDim.x + threadIdx.x;   // [0, E*E)
    int j = idx >> 7, e = idx & 127;
    float ar = 0.f, ai = 0.f;
    for (int m = 0; m < E; ++m) {
        float tr = wt_re[j*E+m], ti = wt_im[j*E+m];
        float pr = wout_re[m*E+e], pi = wout_im[m*E+e];
        ar += tr*pr - ti*pi;
        ai += tr*pi + ti*pr;
    }
    Wfp_re[j*256 + e]       = bf16s(ar);
    Wfp_re[j*256 + 128 + e] = bf16s(-ai);
    Wfp_im[j*256 + e]       = bf16s(ai);
    Wfp_im[j*256 + 128 + e] = bf16s(ar);
    if (idx < E) {
        float br = bt_re[idx], bi = bt_im[idx];
        for (int m = 0; m < E; ++m) {
            float tr = wt_re[idx*E+m], ti = wt_im[idx*E+m];
            br += tr*bout_re[m] - ti*bout_im[m];
            bi += tr*bout_im[m] + ti*bout_re[m];
        }
        bf_re[idx] = br; bf_im[idx] = bi;
    }
}

// ---------------------------------------------------------------------------
// Kernel 2: MFMA QKV projection, fragment-ready packed outputs.
// Grid 1024: id = ttile*2 + half; half=0 -> re outputs, half=1 -> im.
//   Qpk/Kpk : bf16 [bh][t][32]; q scaled 0.25*log2(e) (attn uses exp2)
//   Vtre/Vtim: bf16 [bh][dh][T] transposed + pi-interleaved per 32-t block
// ---------------------------------------------------------------------------
__global__ __launch_bounds__(256) void qkv_mfma_kernel(
    const float* __restrict__ x_re, const float* __restrict__ x_im,
    const short* __restrict__ Wp_re, const short* __restrict__ Wp_im,
    const float* __restrict__ bin_re, const float* __restrict__ bin_im,
    short* __restrict__ Qpk, short* __restrict__ Kpk,
    short* __restrict__ Vtre, short* __restrict__ Vtim)
{
    int tid  = threadIdx.x;
    int wave = tid >> 6, lane = tid & 63;
    int col  = lane & 15, quad = lane >> 4;
    int id = blockIdx.x;               // [0, 1024)
    int ttile = id >> 1;
    int is_im = id & 1;
    int b  = ttile >> 6;
    int tb = (ttile & 63) * 16 + col;

    // X fragments for 8 k-tiles: B[n=col][k=quad*8+jj], cvt_pk packing
    short8 xf[8];
    #pragma unroll
    for (int kt = 0; kt < 8; ++kt) {
        const float* xs = (kt < 4) ? x_re : x_im;
        const float* p = &xs[((long)(b*E + (kt & 3)*32 + quad*8))*T + tb];
        float v0 = p[0], v1 = p[(long)T], v2 = p[2L*T], v3 = p[3L*T];
        float v4 = p[4L*T], v5 = p[5L*T], v6 = p[6L*T], v7 = p[7L*T];
        __hip_bfloat162* xp = (__hip_bfloat162*)&xf[kt];
        xp[0] = pk2(v0, v1); xp[1] = pk2(v2, v3);
        xp[2] = pk2(v4, v5); xp[3] = pk2(v6, v7);
    }

    const short* Wsel = is_im ? Wp_im : Wp_re;
    const float* bias = is_im ? bin_im : bin_re;
    const f32x4 zero = {0.f,0.f,0.f,0.f};

    for (int ni = 0; ni < 6; ++ni) {
        int jt = wave * 6 + ni;            // [0,24): which*8 + h
        const short* wrow = &Wsel[(jt*16 + col)*256 + quad*8];
        f32x4 acc = zero;
        #pragma unroll
        for (int kt = 0; kt < 8; ++kt) {
            short8 af = *(const short8*)(wrow + kt*32);
            acc = __builtin_amdgcn_mfma_f32_16x16x32_bf16(af, xf[kt], acc, 0, 0, 0);
        }
        int which = jt >> 3;               // 0 q, 1 k, 2 v
        int h = jt & 7;
        float scale = (which == 0) ? QSCALE : 1.0f;
        f32x4 res;
        #pragma unroll
        for (int r = 0; r < 4; ++r) {
            int jg = which*128 + h*16 + quad*4 + r;
            res[r] = (acc[r] + bias[jg]) * scale;
        }
        long bh = b*H + h;
        if (which == 2) {
            // V transposed + pi-interleaved: Vt[bh][dh][blk*32 + pos]
            short* vt = is_im ? Vtim : Vtre;
            int tloc = tb & 31, tblk = tb & ~31;
            int u  = tloc & 15;
            int kk = (u >> 2)*8 + (u & 3) + ((tloc >= 16) ? 4 : 0);
            #pragma unroll
            for (int r = 0; r < 4; ++r)
                vt[(bh*DH + quad*4 + r)*T + tblk + kk] = bf16s(res[r]);
        } else {
            short* qk = (which == 0) ? Qpk : Kpk;
            short4s pk;
            __hip_bfloat162* pp = (__hip_bfloat162*)&pk;
            pp[0] = pk2(res[0], res[1]);
            pp[1] = pk2(res[2], res[3]);
            *(short4s*)&qk[(bh*T + tb)*32 + is_im*16 + quad*4] = pk;
        }
    }
}

// ---------------------------------------------------------------------------
// Kernel 3: MFMA flash attention -- no LDS, in-register P, 32 queries/wave.
// S^T = mfma(kfrag, qfrag); exp2 in place (q pre-scaled by log2e); the 8
// values form a B-fragment P[q=col][kpos] under pi (V stored pi-interleaved).
// PV: oacc = mfma(vtfrag, pfrag, oacc) -> O^T. Rowsum via ones-MFMA.
// Pointer-bump addressing; 2 q-tiles amortize every K/V fragment load.
// Grid: id = qt*64 + bh (8 qt x 64 bh = 512 blocks; XCD pin by bh%8).
// ---------------------------------------------------------------------------
__global__ __launch_bounds__(256) void attn_mfma_kernel(
    const short* __restrict__ Qpk, const short* __restrict__ Kpk,
    const short* __restrict__ Vtre, const short* __restrict__ Vtim,
    short* __restrict__ Opk)
{
    int id   = blockIdx.x;
    int bh   = id & 63;
    int q0   = (id >> 6) * 128;
    int tid  = threadIdx.x;
    int wave = tid >> 6;
    int lane = tid & 63;
    int col  = lane & 15;
    int quad = lane >> 4;

    long kq_base = (long)bh * T * 32;
    int qbase = q0 + wave * 32;

    short8 qfA = *(const short8*)&Qpk[kq_base + (long)(qbase + col)*32 + quad*8];
    short8 qfB = *(const short8*)&Qpk[kq_base + (long)(qbase + 16 + col)*32 + quad*8];

    const short* kp  = &Kpk[kq_base + col*32 + quad*8];
    const short* vrp = &Vtre[(long)bh*DH*T + (long)col*T + quad*8];
    const short* vip = &Vtim[(long)bh*DH*T + (long)col*T + quad*8];

    short8 ones;
    #pragma unroll
    for (int i = 0; i < 8; ++i) ones[i] = (short)0x3F80;   // bf16 1.0

    f32x4 oAr = {0,0,0,0}, oAi = {0,0,0,0}, lA = {0,0,0,0};
    f32x4 oBr = {0,0,0,0}, oBi = {0,0,0,0}, lB = {0,0,0,0};
    const f32x4 zero = {0.f,0.f,0.f,0.f};

    // prologue: tile 0
    short8 kf0 = *(const short8*)kp;
    short8 kf1 = *(const short8*)(kp + 512);
    short8 vr  = *(const short8*)vrp;
    short8 vi  = *(const short8*)vip;
    kp += 1024; vrp += 32; vip += 32;

    for (int i = 0; i < 32; ++i) {
        // prefetch tile i+1 (i=31 reads past this head's rows -- valid ws, unused)
        short8 kf0n = *(const short8*)kp;
        short8 kf1n = *(const short8*)(kp + 512);
        short8 vrn  = *(const short8*)vrp;
        short8 vin  = *(const short8*)vip;
        kp += 1024; vrp += 32; vip += 32;

        f32x4 sA0 = __builtin_amdgcn_mfma_f32_16x16x32_bf16(kf0, qfA, zero, 0, 0, 0);
        f32x4 sA1 = __builtin_amdgcn_mfma_f32_16x16x32_bf16(kf1, qfA, zero, 0, 0, 0);
        f32x4 sB0 = __builtin_amdgcn_mfma_f32_16x16x32_bf16(kf0, qfB, zero, 0, 0, 0);
        f32x4 sB1 = __builtin_amdgcn_mfma_f32_16x16x32_bf16(kf1, qfB, zero, 0, 0, 0);

        short8 pfA, pfB;
        {
            __hip_bfloat162* pa = (__hip_bfloat162*)&pfA;
            pa[0] = pk2(fexp2(sA0[0]), fexp2(sA0[1]));
            pa[1] = pk2(fexp2(sA0[2]), fexp2(sA0[3]));
            pa[2] = pk2(fexp2(sA1[0]), fexp2(sA1[1]));
            pa[3] = pk2(fexp2(sA1[2]), fexp2(sA1[3]));
            __hip_bfloat162* pb = (__hip_bfloat162*)&pfB;
            pb[0] = pk2(fexp2(sB0[0]), fexp2(sB0[1]));
            pb[1] = pk2(fexp2(sB0[2]), fexp2(sB0[3]));
            pb[2] = pk2(fexp2(sB1[0]), fexp2(sB1[1]));
            pb[3] = pk2(fexp2(sB1[2]), fexp2(sB1[3]));
        }

        oAr = __builtin_amdgcn_mfma_f32_16x16x32_bf16(vr, pfA, oAr, 0, 0, 0);
        oAi = __builtin_amdgcn_mfma_f32_16x16x32_bf16(vi, pfA, oAi, 0, 0, 0);
        lA  = __builtin_amdgcn_mfma_f32_16x16x32_bf16(ones, pfA, lA, 0, 0, 0);
        oBr = __builtin_amdgcn_mfma_f32_16x16x32_bf16(vr, pfB, oBr, 0, 0, 0);
        oBi = __builtin_amdgcn_mfma_f32_16x16x32_bf16(vi, pfB, oBi, 0, 0, 0);
        lB  = __builtin_amdgcn_mfma_f32_16x16x32_bf16(ones, pfB, lB, 0, 0, 0);

        kf0 = kf0n; kf1 = kf1n; vr = vrn; vi = vin;
    }

    int b = bh >> 3, h = bh & 7;
    float invA = 1.0f / lA[0];
    float invB = 1.0f / lB[0];

    long orowA = ((long)(b*T + qbase + col))*256 + h*16 + quad*4;
    {
        short4s pr, pi_;
        __hip_bfloat162* a = (__hip_bfloat162*)&pr;
        a[0] = pk2(oAr[0]*invA, oAr[1]*invA);
        a[1] = pk2(oAr[2]*invA, oAr[3]*invA);
        __hip_bfloat162* c = (__hip_bfloat162*)&pi_;
        c[0] = pk2(oAi[0]*invA, oAi[1]*invA);
        c[1] = pk2(oAi[2]*invA, oAi[3]*invA);
        *(short4s*)&Opk[orowA]       = pr;
        *(short4s*)&Opk[orowA + 128] = pi_;
    }
    long orowB = orowA + 16L*256;
    {
        short4s pr, pi_;
        __hip_bfloat162* a = (__hip_bfloat162*)&pr;
        a[0] = pk2(oBr[0]*invB, oBr[1]*invB);
        a[1] = pk2(oBr[2]*invB, oBr[3]*invB);
        __hip_bfloat162* c = (__hip_bfloat162*)&pi_;
        c[0] = pk2(oBi[0]*invB, oBi[1]*invB);
        c[1] = pk2(oBi[2]*invB, oBi[3]*invB);
        *(short4s*)&Opk[orowB]       = pr;
        *(short4s*)&Opk[orowB + 128] = pi_;
    }
}

// ---------------------------------------------------------------------------
// Kernel 4: MFMA output projection, conversion-free B-operand from Opk.
// ---------------------------------------------------------------------------
__global__ __launch_bounds__(256) void outproj_mfma_kernel(
    const short* __restrict__ Opk,
    const short* __restrict__ Wfp_re, const short* __restrict__ Wfp_im,
    const float* __restrict__ bf_re, const float* __restrict__ bf_im,
    float* __restrict__ out)
{
    int tid  = threadIdx.x;
    int wave = tid >> 6, lane = tid & 63;
    int col  = lane & 15, quad = lane >> 4;
    int ttile = blockIdx.x;            // [0,512)
    int b  = ttile >> 6;
    int tb = (ttile & 63) * 16 + col;
    long trow = (long)b*T + tb;

    short8 xf[8];
    #pragma unroll
    for (int kt = 0; kt < 8; ++kt)
        xf[kt] = *(const short8*)&Opk[trow*256 + kt*32 + quad*8];

    const f32x4 zero = {0.f,0.f,0.f,0.f};
    #pragma unroll
    for (int ni = 0; ni < 4; ++ni) {
        int nt = wave * 4 + ni;            // [0,16)
        int is_im = nt >= 8;
        int jt = is_im ? nt - 8 : nt;      // [0,8)
        const short* Wsel = is_im ? Wfp_im : Wfp_re;
        const short* wrow = &Wsel[(jt*16 + col)*256 + quad*8];
        f32x4 acc = zero;
        #pragma unroll
        for (int kt = 0; kt < 8; ++kt) {
            short8 af = *(const short8*)(wrow + kt*32);
            acc = __builtin_amdgcn_mfma_f32_16x16x32_bf16(af, xf[kt], acc, 0, 0, 0);
        }
        const float* bias = is_im ? bf_im : bf_re;
        long part = is_im ? (long)B*E*T : 0;
        #pragma unroll
        for (int r = 0; r < 4; ++r) {
            int j = jt*16 + quad*4 + r;
            out[part + ((long)(b*E + j))*T + tb] = acc[r] + bias[j];
        }
    }
}

// ---------------------------------------------------------------------------
extern "C" void kernel_launch(void* const* d_in, const int* in_sizes, int n_in,
                              void* d_out, int out_size, void* d_ws, size_t ws_size,
                              hipStream_t stream)
{
    const float* x_re    = (const float*)d_in[0];
    const float* x_im    = (const float*)d_in[1];
    const float* win_re  = (const float*)d_in[2];
    const float* win_im  = (const float*)d_in[3];
    const float* bin_re  = (const float*)d_in[4];
    const float* bin_im  = (const float*)d_in[5];
    const float* wout_re = (const float*)d_in[6];
    const float* wout_im = (const float*)d_in[7];
    const float* bout_re = (const float*)d_in[8];
    const float* bout_im = (const float*)d_in[9];
    const float* wt_re   = (const float*)d_in[10];
    const float* wt_im   = (const float*)d_in[11];
    const float* bt_re   = (const float*)d_in[12];
    const float* bt_im   = (const float*)d_in[13];
    float* out = (float*)d_out;

    // workspace layout (shorts/floats)
    short* Qpk  = (short*)d_ws;                       // 64*1024*32 = 2M shorts
    short* Kpk  = Qpk + (long)B*H*T*32;
    short* Vtre = Kpk + (long)B*H*T*32;               // 64*16*1024 = 1M shorts
    short* Vtim = Vtre + (long)B*H*DH*T;
    short* Opk  = Vtim + (long)B*H*DH*T;              // 8*1024*256 = 2M shorts
    short* Wp_re  = Opk + (long)B*T*256;
    short* Wp_im  = Wp_re + E3*256;
    short* Wfp_re = Wp_im + E3*256;
    short* Wfp_im = Wfp_re + E*256;
    float* bf_re  = (float*)(Wfp_im + E*256);
    float* bf_im  = bf_re + E;

    pack_win_kernel<<<dim3(E3*E/256), dim3(256), 0, stream>>>(
        win_re, win_im, Wp_re, Wp_im);

    fuse_weights_kernel<<<dim3(E*E/256), dim3(256), 0, stream>>>(
        wout_re, wout_im, bout_re, bout_im, wt_re, wt_im, bt_re, bt_im,
        Wfp_re, Wfp_im, bf_re, bf_im);

    qkv_mfma_kernel<<<dim3(T*B/16*2), dim3(256), 0, stream>>>(
        x_re, x_im, Wp_re, Wp_im, bin_re, bin_im,
        Qpk, Kpk, Vtre, Vtim);

    attn_mfma_kernel<<<dim3(8 * 64), dim3(256), 0, stream>>>(
        Qpk, Kpk, Vtre, Vtim, Opk);

    outproj_mfma_kernel<<<dim3(T*B/16), dim3(256), 0, stream>>>(
        Opk, Wfp_re, Wfp_im, bf_re, bf_im, out);
}